// Round 1
// baseline (668.727 us; speedup 1.0000x reference)
//
#include <hip/hip_runtime.h>
#include <math.h>

// GlobalAttentionPooling: gate = x @ Wg + bg; segment-softmax(gate) over sorted
// `batch`; out[g] = sum_i attn_i * x_i.  Single pass over x (512 MB) using
// online softmax, one block (256 thr) per segment.

#define DIM 256
#define RCHUNK 8

__device__ __forceinline__ int lower_bound(const int* __restrict__ b, int n, int key) {
    int lo = 0, hi = n;
    while (lo < hi) {
        int mid = (lo + hi) >> 1;
        if (b[mid] < key) lo = mid + 1; else hi = mid;
    }
    return lo;
}

__global__ __launch_bounds__(256)
void gap_fused_kernel(const float* __restrict__ x,
                      const int* __restrict__ batch,
                      const float* __restrict__ Wg,
                      const float* __restrict__ bg,
                      float* __restrict__ out,
                      int N) {
    const int g   = blockIdx.x;
    const int tid = threadIdx.x;

    // Segment bounds (all threads redundantly; batch reads hit cache)
    const int start = lower_bound(batch, N, g);
    const int end   = lower_bound(batch, N, g + 1);

    __shared__ float s_rows[RCHUNK * DIM];   // 8 KB staging
    __shared__ float s_gates[RCHUNK];

    if (start >= end) {                       // empty segment -> zeros
        out[(size_t)g * DIM + tid] = 0.0f;
        return;
    }

    const int lane = tid & 63;
    const int wv   = tid >> 6;                // wave id 0..3
    const float4 wgv  = ((const float4*)Wg)[lane];  // Wg[4*lane .. 4*lane+3]
    const float  bias = bg[0];

    const int len = end - start;
    const float4* __restrict__ x4 = (const float4*)x + (size_t)start * (DIM / 4);
    float4* s4 = (float4*)s_rows;

    float m = -INFINITY;   // running max
    float l = 0.0f;        // running denom
    float acc = 0.0f;      // this thread's output column (d = tid)

    for (int c = 0; c < len; c += RCHUNK) {
        __syncthreads();   // previous iteration's LDS readers done

        // ---- stage up to 8 rows; wave w owns rows c+w and c+w+4 ----
        const int r0 = c + wv;
        const int r1 = c + wv + 4;
        float g0 = -INFINITY, g1 = -INFINITY;

        if (r0 < len) {
            float4 v = x4[(size_t)r0 * 64 + lane];
            s4[wv * 64 + lane] = v;
            float d = fmaf(v.x, wgv.x, fmaf(v.y, wgv.y, fmaf(v.z, wgv.z, v.w * wgv.w)));
            #pragma unroll
            for (int off = 32; off; off >>= 1) d += __shfl_xor(d, off);
            g0 = d + bias;
        } else {
            s4[wv * 64 + lane] = make_float4(0.f, 0.f, 0.f, 0.f);
        }
        if (r1 < len) {
            float4 v = x4[(size_t)r1 * 64 + lane];
            s4[(wv + 4) * 64 + lane] = v;
            float d = fmaf(v.x, wgv.x, fmaf(v.y, wgv.y, fmaf(v.z, wgv.z, v.w * wgv.w)));
            #pragma unroll
            for (int off = 32; off; off >>= 1) d += __shfl_xor(d, off);
            g1 = d + bias;
        } else {
            s4[(wv + 4) * 64 + lane] = make_float4(0.f, 0.f, 0.f, 0.f);
        }
        if (lane == 0) {
            s_gates[wv]     = g0;
            s_gates[wv + 4] = g1;
        }
        __syncthreads();

        // ---- online softmax update; every thread owns column d = tid ----
        float gl[RCHUNK];
        float cmax = -INFINITY;
        #pragma unroll
        for (int i = 0; i < RCHUNK; ++i) {
            gl[i] = s_gates[i];
            cmax = fmaxf(cmax, gl[i]);
        }
        const float nm    = fmaxf(m, cmax);       // finite: chunk has >=1 valid row
        const float alpha = __expf(m - nm);       // 0 on first chunk (m = -inf)
        acc *= alpha;
        l   *= alpha;
        #pragma unroll
        for (int i = 0; i < RCHUNK; ++i) {
            const float p = __expf(gl[i] - nm);   // 0 for invalid (-inf) rows
            l += p;
            acc = fmaf(p, s_rows[i * DIM + tid], acc);
        }
        m = nm;
    }

    out[(size_t)g * DIM + tid] = acc / l;
}

extern "C" void kernel_launch(void* const* d_in, const int* in_sizes, int n_in,
                              void* d_out, int out_size, void* d_ws, size_t ws_size,
                              hipStream_t stream) {
    const float* x     = (const float*)d_in[0];
    const int*   batch = (const int*)d_in[1];
    const float* Wg    = (const float*)d_in[2];
    const float* bg    = (const float*)d_in[3];
    float*       out   = (float*)d_out;

    const int N = in_sizes[1];          // 500000 nodes
    const int G = out_size / DIM;       // 4096 graphs

    gap_fused_kernel<<<G, DIM, 0, stream>>>(x, batch, Wg, bg, out, N);
}

// Round 2
// 660.511 us; speedup vs baseline: 1.0124x; 1.0124x over previous
//
#include <hip/hip_runtime.h>
#include <math.h>

// GlobalAttentionPooling, fused single pass.
// One block (4 waves) per segment; wave w owns rows {start+w, start+w+4, ...}.
// Online softmax state (m, l, acc[4 cols/lane]) lives entirely in registers --
// a row's float4-per-lane load layout IS the accumulator layout, so no LDS row
// staging and no barriers in the main loop. Single end-of-block 4-way merge.

#define DIM 256

__device__ __forceinline__ int lower_bound(const int* __restrict__ b, int n, int key) {
    int lo = 0, hi = n;
    while (lo < hi) {
        int mid = (lo + hi) >> 1;
        if (b[mid] < key) lo = mid + 1; else hi = mid;
    }
    return lo;
}

__global__ __launch_bounds__(256)
void gap_fused_kernel(const float* __restrict__ x,
                      const int* __restrict__ batch,
                      const float* __restrict__ Wg,
                      const float* __restrict__ bg,
                      float* __restrict__ out,
                      int N) {
    const int g    = blockIdx.x;
    const int tid  = threadIdx.x;
    const int lane = tid & 63;
    const int wv   = tid >> 6;

    const int start = lower_bound(batch, N, g);
    const int end   = lower_bound(batch, N, g + 1);

    __shared__ float s_ml[8];           // m[0..3], l[4..7]
    __shared__ float s_acc[4 * DIM];    // 4 KB

    if (start >= end) {                 // empty segment -> zeros
        out[(size_t)g * DIM + tid] = 0.0f;
        return;
    }

    const float4 wgv  = ((const float4*)Wg)[lane];   // Wg[4*lane .. 4*lane+3]
    const float  bias = bg[0];
    const int    len  = end - start;
    const float4* __restrict__ x4 = (const float4*)x + (size_t)start * (DIM / 4);

    float  m   = -INFINITY;
    float  l   = 0.0f;
    float4 acc = make_float4(0.f, 0.f, 0.f, 0.f);

    // Main loop: 2 rows per iteration (r, r+4), wave-uniform predicates.
    for (int r = wv; r < len; r += 8) {
        const int  r2   = r + 4;
        const bool has2 = (r2 < len);                 // wave-uniform
        float4 v0 = x4[(size_t)r * 64 + lane];
        float4 v1 = make_float4(0.f, 0.f, 0.f, 0.f);
        if (has2) v1 = x4[(size_t)r2 * 64 + lane];

        float d0 = fmaf(v0.x, wgv.x, fmaf(v0.y, wgv.y, fmaf(v0.z, wgv.z, v0.w * wgv.w)));
        float d1 = fmaf(v1.x, wgv.x, fmaf(v1.y, wgv.y, fmaf(v1.z, wgv.z, v1.w * wgv.w)));
        #pragma unroll
        for (int off = 32; off; off >>= 1) {          // two interleaved butterflies
            d0 += __shfl_xor(d0, off);
            d1 += __shfl_xor(d1, off);
        }
        const float g0 = d0 + bias;
        const float g1 = has2 ? (d1 + bias) : -INFINITY;

        const float nm    = fmaxf(m, fmaxf(g0, g1)); // finite: row r always valid
        const float alpha = __expf(m - nm);          // 0 on first iteration
        const float p0    = __expf(g0 - nm);
        const float p1    = __expf(g1 - nm);         // 0 when !has2
        l = fmaf(l, alpha, p0 + p1);
        acc.x = fmaf(p0, v0.x, fmaf(p1, v1.x, acc.x * alpha));
        acc.y = fmaf(p0, v0.y, fmaf(p1, v1.y, acc.y * alpha));
        acc.z = fmaf(p0, v0.z, fmaf(p1, v1.z, acc.z * alpha));
        acc.w = fmaf(p0, v0.w, fmaf(p1, v1.w, acc.w * alpha));
        m = nm;
    }

    // ---- merge the 4 waves' states (single barrier) ----
    if (lane == 0) { s_ml[wv] = m; s_ml[4 + wv] = l; }   // m,l are wave-uniform
    ((float4*)s_acc)[wv * 64 + lane] = acc;
    __syncthreads();

    const float M = fmaxf(fmaxf(s_ml[0], s_ml[1]), fmaxf(s_ml[2], s_ml[3])); // finite
    float denom = 0.f, val = 0.f;
    #pragma unroll
    for (int w = 0; w < 4; ++w) {
        const float sc = __expf(s_ml[w] - M);        // 0 for idle waves (m=-inf)
        denom = fmaf(s_ml[4 + w], sc, denom);
        val   = fmaf(s_acc[w * DIM + tid], sc, val);
    }
    out[(size_t)g * DIM + tid] = val / denom;
}

extern "C" void kernel_launch(void* const* d_in, const int* in_sizes, int n_in,
                              void* d_out, int out_size, void* d_ws, size_t ws_size,
                              hipStream_t stream) {
    const float* x     = (const float*)d_in[0];
    const int*   batch = (const int*)d_in[1];
    const float* Wg    = (const float*)d_in[2];
    const float* bg    = (const float*)d_in[3];
    float*       out   = (float*)d_out;

    const int N = in_sizes[1];          // 500000 nodes
    const int G = out_size / DIM;       // 4096 graphs

    gap_fused_kernel<<<G, DIM, 0, stream>>>(x, batch, Wg, bg, out, N);
}